// Round 11
// baseline (573.454 us; speedup 1.0000x reference)
//
#include <hip/hip_runtime.h>

#define D 128           // feature dim
#define NB_MAX 512      // supports N <= 131072 (bucket = 256 nodes)
#define STAGE_CAP 12288 // csr_build LDS stage entries
#define NSLICE 8        // feature slices == # XCDs
#define FILLB 2048      // hist/fill grid blocks (mapping must match between the two)

// ---------------------------------------------------------------------------
// bf16 pack (RNE; low 16 bits = even column)
// ---------------------------------------------------------------------------
__device__ __forceinline__ unsigned int pack_bf16(float a, float b) {
    unsigned int ua = __float_as_uint(a), ub = __float_as_uint(b);
    ua = (ua + 0x7fffu + ((ua >> 16) & 1u)) >> 16;
    ub = (ub + 0x7fffu + ((ub >> 16) & 1u)) >> 16;
    return (ub << 16) | (ua & 0xffffu);
}

// ---------------------------------------------------------------------------
// hist: per-(bucket, xcd-label) counts + out-degree histogram.
// label = blockIdx & 7; fill uses the SAME grid/stride so labels match.
// ---------------------------------------------------------------------------
__global__ __launch_bounds__(256) void hist_kernel(const int* __restrict__ src,
                                                   const int* __restrict__ dst,
                                                   int* __restrict__ outdeg,
                                                   int* __restrict__ cur8, int E) {
    const int xcd = blockIdx.x & 7;
    int i = blockIdx.x * 256 + threadIdx.x;
    const int stride = FILLB * 256;
    for (; i < E; i += stride) {
        atomicAdd(&outdeg[src[i]], 1);
        atomicAdd(&cur8[((dst[i] >> 8) << 3) + xcd], 1);
    }
}

// ---------------------------------------------------------------------------
// scan: exclusive scan of cur8[nb*8] in place (counts -> start cursors);
// bucket bases bb[b] = cursor of cell (b,0); bb[nb] = E. One block.
// ---------------------------------------------------------------------------
__global__ __launch_bounds__(1024) void scan_kernel(int* __restrict__ cur8,
                                                    int* __restrict__ bb,
                                                    int nb, int E) {
    __shared__ int red[1024];
    const int t = threadIdx.x;
    const int ncell = nb * 8;
    const int i0 = t * 4;
    int v[4]; int s = 0;
    #pragma unroll
    for (int q = 0; q < 4; ++q) {
        int idx = i0 + q;
        v[q] = (idx < ncell) ? cur8[idx] : 0;
        s += v[q];
    }
    red[t] = s;
    __syncthreads();
    for (int d = 1; d < 1024; d <<= 1) {
        int x = (t >= d) ? red[t - d] : 0;
        __syncthreads();
        red[t] += x;
        __syncthreads();
    }
    int excl = red[t] - s;
    #pragma unroll
    for (int q = 0; q < 4; ++q) {
        int idx = i0 + q;
        if (idx < ncell) {
            cur8[idx] = excl;
            if ((idx & 7) == 0) bb[idx >> 3] = excl;
        }
        excl += v[q];
    }
    if (t == 0) bb[nb] = E;
}

// ---------------------------------------------------------------------------
// fill + GEMM (fused launch): blocks [0,FILLB) scatter edges into the
// bucket-major pairs array via global cursors (adjacent slots per cell =>
// L2 write-combining; per-XCD cells => no cross-XCD line ping-pong).
// Blocks [FILLB,...) compute hw = bf16(h @ W), XCD-sliced layout
// hw[(cp>>3)*N*8 + row*8 + (cp&7)].
// ---------------------------------------------------------------------------
__global__ __launch_bounds__(256) void fill_gemm(const float* __restrict__ h,
                                                 const float* __restrict__ Wm,
                                                 const int* __restrict__ src,
                                                 const int* __restrict__ dst,
                                                 int* __restrict__ cur8,
                                                 unsigned int* __restrict__ pairs,
                                                 unsigned int* __restrict__ hw,
                                                 int E, int N) {
    const int bid = (int)blockIdx.x;
    const int t   = threadIdx.x;

    if (bid < FILLB) {
        const int xcd = bid & 7;
        int i = bid * 256 + t;
        const int stride = FILLB * 256;
        for (; i < E; i += stride) {
            int d = dst[i];
            int s = src[i];
            int slot = atomicAdd(&cur8[((d >> 8) << 3) + xcd], 1);
            pairs[slot] = ((unsigned int)(d & 255) << 24) | (unsigned int)s;
        }
    } else {
        __shared__ __align__(16) float tile[64][D];
        const int r0 = (bid - FILLB) * 64;

        #pragma unroll
        for (int i = 0; i < 8; ++i) {
            int flat4 = i * 256 + t;
            int r     = flat4 >> 5;
            int c4    = flat4 & 31;
            int gr    = r0 + r;
            float4 v  = make_float4(0.f, 0.f, 0.f, 0.f);
            if (gr < N) v = reinterpret_cast<const float4*>(h + (size_t)gr * D)[c4];
            reinterpret_cast<float4*>(&tile[r][c4 * 4])[0] = v;
        }
        __syncthreads();

        const int wsel = t >> 6;
        const int cp   = t & 63;
        const int j0   = cp * 2;

        float acc[16][2];
        #pragma unroll
        for (int r = 0; r < 16; ++r) { acc[r][0] = 0.f; acc[r][1] = 0.f; }

        for (int k = 0; k < D; k += 4) {
            float2 w[4];
            #pragma unroll
            for (int kk = 0; kk < 4; ++kk)
                w[kk] = reinterpret_cast<const float2*>(Wm + (size_t)(k + kk) * D + j0)[0];
            #pragma unroll
            for (int r = 0; r < 16; ++r) {
                float4 a = reinterpret_cast<const float4*>(&tile[wsel * 16 + r][k])[0];
                acc[r][0] += a.x * w[0].x + a.y * w[1].x + a.z * w[2].x + a.w * w[3].x;
                acc[r][1] += a.x * w[0].y + a.y * w[1].y + a.z * w[2].y + a.w * w[3].y;
            }
        }

        const size_t slice_off = (size_t)(cp >> 3) * N * 8 + (cp & 7);
        #pragma unroll
        for (int r = 0; r < 16; ++r) {
            int gr = r0 + wsel * 16 + r;
            if (gr < N) hw[slice_off + (size_t)gr * 8] = pack_bf16(acc[r][0], acc[r][1]);
        }
    }
}

// ---------------------------------------------------------------------------
// csr_build: bucket segment is CONTIGUOUS [bb[b], bb[b+1]) — counting sort by
// local dst -> CSR segment + off[] entries. No section tables, no binsearch.
// ---------------------------------------------------------------------------
__global__ __launch_bounds__(256) void csr_build(const unsigned int* __restrict__ pairs,
                                                 const int* __restrict__ bb,
                                                 int* __restrict__ off,
                                                 int* __restrict__ csr,
                                                 int N, int E) {
    __shared__ int dhist[256];
    __shared__ int dcur[256];
    __shared__ unsigned int stage[STAGE_CAP];

    const int t = threadIdx.x;
    const int b = blockIdx.x;
    const int base_g = bb[b];
    const int total  = bb[b + 1] - base_g;

    dhist[t] = 0;
    __syncthreads();

    for (int j = t; j < total; j += 256)
        atomicAdd(&dhist[pairs[base_g + j] >> 24], 1);
    __syncthreads();

    if (t == 0) {
        int acc = 0;
        for (int i = 0; i < 256; ++i) { int v = dhist[i]; dhist[i] = acc; acc += v; }
    }
    __syncthreads();

    {
        int node = (b << 8) + t;
        if (node < N) off[node] = base_g + dhist[t];
        if (b == (int)gridDim.x - 1 && t == 0) off[N] = E;
    }
    dcur[t] = dhist[t];
    __syncthreads();

    for (int j = t; j < total; j += 256) {
        unsigned int p = pairs[base_g + j];
        int slot = atomicAdd(&dcur[p >> 24], 1);
        unsigned int s = p & 0xFFFFFFu;
        if (slot < STAGE_CAP) stage[slot] = s;
        else csr[base_g + slot] = (int)s;   // pathological-skew safety
    }
    __syncthreads();

    int lim = min(total, STAGE_CAP);
    for (int j = t; j < lim; j += 256) csr[base_g + j] = (int)stage[j];
}

// ---------------------------------------------------------------------------
// XCD-sliced aggregation, wave = 8 nodes x 8 colpair-lanes, ILP-4 inner loop
// (round-7 version).
// ---------------------------------------------------------------------------
__global__ __launch_bounds__(256) void aggregate_sliced(const unsigned int* __restrict__ hw,
                                                        const int* __restrict__ off,
                                                        const int* __restrict__ csr,
                                                        const int* __restrict__ outdeg,
                                                        const float* __restrict__ bias,
                                                        float* __restrict__ out, int N) {
    const int s    = blockIdx.x & (NSLICE - 1);
    const int wav  = threadIdx.x >> 6;
    const int lane = threadIdx.x & 63;
    const int grp  = lane >> 3;      // node sub-index within wave (0..7)
    const int cp   = lane & 7;       // colpair within slice (0..7)
    const int gw   = ((int)blockIdx.x >> 3) * 4 + wav;   // wave id within slice
    const int nw   = ((int)gridDim.x >> 3) * 4;          // waves per slice

    const unsigned int* hws = hw + (size_t)s * N * 8;
    const float2 bb = reinterpret_cast<const float2*>(bias)[s * 8 + cp];

    for (int n0 = gw * 8; n0 < N; n0 += nw * 8) {
        const int n = n0 + grp;
        int e0 = 0, e1 = 0;
        if (n < N) { e0 = off[n]; e1 = off[n + 1]; }

        float ax = 0.f, ay = 0.f;
        int e = e0;
        for (; e + 4 <= e1; e += 4) {
            int i0 = csr[e], i1 = csr[e + 1], i2 = csr[e + 2], i3 = csr[e + 3];
            unsigned int u0 = hws[i0 * 8 + cp];
            unsigned int u1 = hws[i1 * 8 + cp];
            unsigned int u2 = hws[i2 * 8 + cp];
            unsigned int u3 = hws[i3 * 8 + cp];
            ax += __uint_as_float(u0 << 16) + __uint_as_float(u1 << 16)
                + __uint_as_float(u2 << 16) + __uint_as_float(u3 << 16);
            ay += __uint_as_float(u0 & 0xffff0000u) + __uint_as_float(u1 & 0xffff0000u)
                + __uint_as_float(u2 & 0xffff0000u) + __uint_as_float(u3 & 0xffff0000u);
        }
        for (; e < e1; ++e) {
            unsigned int u = hws[csr[e] * 8 + cp];
            ax += __uint_as_float(u << 16);
            ay += __uint_as_float(u & 0xffff0000u);
        }

        if (n < N) {
            float sc = 1.0f / (float)outdeg[n];
            float2 o;
            o.x = ax * sc + bb.x;
            o.y = ay * sc + bb.y;
            reinterpret_cast<float2*>(out + (size_t)n * D + s * 16)[cp] = o;
        }
    }
}

// ---------------------------------------------------------------------------
// Tier-3 fallback: atomic scatter path (shape-independent)
// ---------------------------------------------------------------------------
__global__ void deg_kernel(const int* __restrict__ src, int* __restrict__ deg, int E) {
    int i = blockIdx.x * blockDim.x + threadIdx.x;
    int stride = gridDim.x * blockDim.x;
    for (; i < E; i += stride) atomicAdd(&deg[src[i]], 1);
}

__global__ void scatter_kernel(const float* __restrict__ h,
                               const int* __restrict__ src,
                               const int* __restrict__ dst,
                               float* __restrict__ agg, int E) {
    int wave   = (int)((blockIdx.x * blockDim.x + threadIdx.x) >> 6);
    int lane   = threadIdx.x & 63;
    int nwaves = (int)((gridDim.x * blockDim.x) >> 6);
    for (int e = wave; e < E; e += nwaves) {
        int s = src[e];
        int d = dst[e];
        const float2 v = reinterpret_cast<const float2*>(h + (size_t)s * D)[lane];
        float* arow = agg + (size_t)d * D + lane * 2;
        atomicAdd(arow + 0, v.x);
        atomicAdd(arow + 1, v.y);
    }
}

__global__ __launch_bounds__(256) void gemm_finish(float* __restrict__ out,
                                                   const float* __restrict__ Wm,
                                                   const float* __restrict__ bias,
                                                   const int* __restrict__ deg,
                                                   int N) {
    __shared__ __align__(16) float tile[64][D];
    const int r0 = blockIdx.x * 64;
    const int t  = threadIdx.x;

    #pragma unroll
    for (int i = 0; i < 8; ++i) {
        int flat4 = i * 256 + t;
        int r     = flat4 >> 5;
        int c4    = flat4 & 31;
        int gr    = r0 + r;
        float4 v  = make_float4(0.f, 0.f, 0.f, 0.f);
        if (gr < N) v = reinterpret_cast<const float4*>(out + (size_t)gr * D)[c4];
        reinterpret_cast<float4*>(&tile[r][c4 * 4])[0] = v;
    }
    __syncthreads();

    const int wsel = t >> 6;
    const int j0   = (t & 63) * 2;

    float acc[16][2];
    #pragma unroll
    for (int r = 0; r < 16; ++r) { acc[r][0] = 0.f; acc[r][1] = 0.f; }

    for (int k = 0; k < D; k += 4) {
        float2 w[4];
        #pragma unroll
        for (int kk = 0; kk < 4; ++kk)
            w[kk] = reinterpret_cast<const float2*>(Wm + (size_t)(k + kk) * D + j0)[0];
        #pragma unroll
        for (int r = 0; r < 16; ++r) {
            float4 a = reinterpret_cast<const float4*>(&tile[wsel * 16 + r][k])[0];
            acc[r][0] += a.x * w[0].x + a.y * w[1].x + a.z * w[2].x + a.w * w[3].x;
            acc[r][1] += a.x * w[0].y + a.y * w[1].y + a.z * w[2].y + a.w * w[3].y;
        }
    }

    const float2 bb = reinterpret_cast<const float2*>(bias + j0)[0];
    #pragma unroll
    for (int r = 0; r < 16; ++r) {
        int gr = r0 + wsel * 16 + r;
        if (gr < N) {
            float sc = 1.0f / (float)deg[gr];
            float2 o;
            o.x = acc[r][0] * sc + bb.x;
            o.y = acc[r][1] * sc + bb.y;
            reinterpret_cast<float2*>(out + (size_t)gr * D + j0)[0] = o;
        }
    }
}

// ---------------------------------------------------------------------------
extern "C" void kernel_launch(void* const* d_in, const int* in_sizes, int n_in,
                              void* d_out, int out_size, void* d_ws, size_t ws_size,
                              hipStream_t stream) {
    const float* h   = (const float*)d_in[0];
    const float* Wm  = (const float*)d_in[1];
    const float* bia = (const float*)d_in[2];
    const int*   src = (const int*)d_in[3];
    const int*   dst = (const int*)d_in[4];
    float*       out = (float*)d_out;

    const int N = in_sizes[0] / D;   // 100000
    const int E = in_sizes[3];       // 1700000

    const int nb      = (N + 255) >> 8;
    const int gblocks = (N + 63) / 64;

    // ws (ints): outdeg[N] | cur8[NB_MAX*8] | bb[NB_MAX+1] | off[N+1] |
    //            pairs[E] | csr[E] | hw[N*64]
    size_t tier1_ints = (size_t)N + (size_t)NB_MAX * 8 + (NB_MAX + 1) + (N + 1)
                      + (size_t)E + (size_t)E + (size_t)N * 64;

    bool shape_ok = (N < (1 << 24)) && nb <= NB_MAX;

    if (shape_ok && ws_size >= tier1_ints * sizeof(int)) {
        int* outdeg = (int*)d_ws;
        int* cur8   = outdeg + N;
        int* bb     = cur8 + (size_t)NB_MAX * 8;
        int* off    = bb + (NB_MAX + 1);
        unsigned int* pairs = (unsigned int*)(off + (N + 1));
        int* csr    = (int*)(pairs + (size_t)E);
        unsigned int* hw = (unsigned int*)(csr + E);

        // zero outdeg + cur8 (contiguous)
        hipMemsetAsync(outdeg, 0, ((size_t)N + (size_t)NB_MAX * 8) * sizeof(int), stream);

        hist_kernel<<<FILLB, 256, 0, stream>>>(src, dst, outdeg, cur8, E);
        scan_kernel<<<1, 1024, 0, stream>>>(cur8, bb, nb, E);
        fill_gemm<<<FILLB + gblocks, 256, 0, stream>>>(h, Wm, src, dst, cur8,
                                                       pairs, hw, E, N);
        csr_build<<<nb, 256, 0, stream>>>(pairs, bb, off, csr, N, E);
        aggregate_sliced<<<2048, 256, 0, stream>>>(hw, off, csr, outdeg, bia, out, N);
    } else {
        // fallback: atomic scatter path
        int* deg = (int*)d_ws;
        hipMemsetAsync(out, 0, (size_t)out_size * sizeof(float), stream);
        hipMemsetAsync(deg, 0, (size_t)N * sizeof(int), stream);
        deg_kernel<<<2048, 256, 0, stream>>>(src, deg, E);
        scatter_kernel<<<8192, 256, 0, stream>>>(h, src, dst, out, E);
        gemm_finish<<<(N + 63) / 64, 256, 0, stream>>>(out, Wm, bia, deg, N);
    }
}

// Round 12
// 245.963 us; speedup vs baseline: 2.3315x; 2.3315x over previous
//
#include <hip/hip_runtime.h>

#define D 128           // feature dim
#define CHUNK 8192      // edges per partition block
#define NCHUNK_MAX 256  // supports E <= 2M
#define NB_MAX 512      // supports N <= 131072 (bucket = 256 nodes)
#define STAGE_CAP 12288 // csr_build LDS stage entries

// ---------------------------------------------------------------------------
// bf16 pack (RNE; low 16 bits = even column)
// ---------------------------------------------------------------------------
__device__ __forceinline__ unsigned int pack_bf16(float a, float b) {
    unsigned int ua = __float_as_uint(a), ub = __float_as_uint(b);
    ua = (ua + 0x7fffu + ((ua >> 16) & 1u)) >> 16;
    ub = (ub + 0x7fffu + ((ub >> 16) & 1u)) >> 16;
    return (ub << 16) | (ua & 0xffffu);
}

// ---------------------------------------------------------------------------
// Phase 1 (fused, round-7 config): blocks [0,nchunk) partition edges by dst
// bucket (dst>>8); blocks [nchunk,...) compute hw = bf16(h @ W) in FLAT
// layout hw[row*64 + cp]  (round-5 measured-90us aggregate layout).
// ---------------------------------------------------------------------------
struct Phase1Smem {
    union {
        struct {
            int hist[NB_MAX];
            int lofs[NB_MAX];
            int cur[NB_MAX];
            unsigned int stage[CHUNK];
        } p;
        struct {
            float tile[64][D];
        } g;
    };
};

__global__ __launch_bounds__(256) void phase1(const float* __restrict__ h,
                                              const float* __restrict__ Wm,
                                              const int* __restrict__ src,
                                              const int* __restrict__ dst,
                                              unsigned int* __restrict__ pairs,
                                              int* __restrict__ cnt_g,
                                              int* __restrict__ loff_g,
                                              int* __restrict__ outdeg,
                                              int* __restrict__ tot,
                                              unsigned int* __restrict__ hw,
                                              int E, int nb, int nchunk, int N) {
    __shared__ Phase1Smem sm;
    const int t = threadIdx.x;

    if ((int)blockIdx.x < nchunk) {
        // ---------------- partition role ----------------
        const int c  = blockIdx.x;
        const int e0 = c * CHUNK;
        const int n  = min(CHUNK, E - e0);

        for (int i = t; i < nb; i += 256) sm.p.hist[i] = 0;
        __syncthreads();

        // pass 1: bucket histogram
        for (int i = t; i < n; i += 256) {
            int d = dst[e0 + i];
            atomicAdd(&sm.p.hist[d >> 8], 1);
        }
        __syncthreads();

        if (t == 0) {
            int acc = 0;
            for (int i = 0; i < nb; ++i) { sm.p.lofs[i] = acc; acc += sm.p.hist[i]; }
        }
        __syncthreads();

        // export tables + bucket totals + init cursors
        for (int i = t; i < nb; i += 256) {
            int hv = sm.p.hist[i];
            cnt_g[(size_t)c * nb + i]  = hv;
            loff_g[(size_t)c * nb + i] = sm.p.lofs[i];
            if (hv) atomicAdd(&tot[i], hv);
            sm.p.cur[i] = sm.p.lofs[i];
        }
        __syncthreads();

        // pass 2: scatter into LDS stage + out-degree histogram
        for (int i = t; i < n; i += 256) {
            int d = dst[e0 + i];
            int s = src[e0 + i];
            atomicAdd(&outdeg[s], 1);
            int slot = atomicAdd(&sm.p.cur[d >> 8], 1);
            sm.p.stage[slot] = ((unsigned int)(d & 255) << 24) | (unsigned int)s;
        }
        __syncthreads();

        // pass 3: dense streamout
        for (int i = t; i < n; i += 256) pairs[e0 + i] = sm.p.stage[i];
    } else {
        // ---------------- GEMM role ----------------
        const int r0 = ((int)blockIdx.x - nchunk) * 64;

        #pragma unroll
        for (int i = 0; i < 8; ++i) {
            int flat4 = i * 256 + t;
            int r     = flat4 >> 5;
            int c4    = flat4 & 31;
            int gr    = r0 + r;
            float4 v  = make_float4(0.f, 0.f, 0.f, 0.f);
            if (gr < N) v = reinterpret_cast<const float4*>(h + (size_t)gr * D)[c4];
            reinterpret_cast<float4*>(&sm.g.tile[r][c4 * 4])[0] = v;
        }
        __syncthreads();

        const int wsel = t >> 6;
        const int cp   = t & 63;
        const int j0   = cp * 2;

        float acc[16][2];
        #pragma unroll
        for (int r = 0; r < 16; ++r) { acc[r][0] = 0.f; acc[r][1] = 0.f; }

        for (int k = 0; k < D; k += 4) {
            float2 w[4];
            #pragma unroll
            for (int kk = 0; kk < 4; ++kk)
                w[kk] = reinterpret_cast<const float2*>(Wm + (size_t)(k + kk) * D + j0)[0];
            #pragma unroll
            for (int r = 0; r < 16; ++r) {
                float4 a = reinterpret_cast<const float4*>(&sm.g.tile[wsel * 16 + r][k])[0];
                acc[r][0] += a.x * w[0].x + a.y * w[1].x + a.z * w[2].x + a.w * w[3].x;
                acc[r][1] += a.x * w[0].y + a.y * w[1].y + a.z * w[2].y + a.w * w[3].y;
            }
        }

        // FLAT layout (round-5): one uint per (row, colpair)
        #pragma unroll
        for (int r = 0; r < 16; ++r) {
            int gr = r0 + wsel * 16 + r;
            if (gr < N) hw[(size_t)gr * 64 + cp] = pack_bf16(acc[r][0], acc[r][1]);
        }
    }
}

// ---------------------------------------------------------------------------
// csr_build: per-bucket counting sort by local dst -> CSR segment + off[].
// (round-7 version, unchanged)
// ---------------------------------------------------------------------------
__global__ __launch_bounds__(256) void csr_build(const unsigned int* __restrict__ pairs,
                                                 const int* __restrict__ cnt_g,
                                                 const int* __restrict__ loff_g,
                                                 const int* __restrict__ tot,
                                                 int* __restrict__ off,
                                                 int* __restrict__ csr,
                                                 int nb, int nchunk, int N, int E) {
    __shared__ int sec_base[NCHUNK_MAX + 1];
    __shared__ int sec_lo[NCHUNK_MAX];
    __shared__ int dhist[256];
    __shared__ int dcur[256];
    __shared__ int red[256];
    __shared__ int sh_base;
    __shared__ unsigned int stage[STAGE_CAP];

    const int t = threadIdx.x;
    const int b = blockIdx.x;

    // global base = sum of tot[i], i < b
    {
        int partial = 0;
        for (int i = t; i < b; i += 256) partial += tot[i];
        red[t] = partial;
        __syncthreads();
        for (int o = 128; o > 0; o >>= 1) {
            if (t < o) red[t] += red[t + o];
            __syncthreads();
        }
        if (t == 0) sh_base = red[0];
    }

    for (int c = t; c < nchunk; c += 256) {
        sec_base[c] = cnt_g[(size_t)c * nb + b];
        sec_lo[c]   = loff_g[(size_t)c * nb + b];
    }
    dhist[t] = 0;
    __syncthreads();
    if (t == 0) {
        int acc = 0;
        for (int c = 0; c < nchunk; ++c) { int v = sec_base[c]; sec_base[c] = acc; acc += v; }
        sec_base[nchunk] = acc;
    }
    __syncthreads();

    const int total  = sec_base[nchunk];
    const int base_g = sh_base;

    for (int j = t; j < total; j += 256) {
        int lo = 0, hi = nchunk - 1;
        while (lo < hi) { int mid = (lo + hi + 1) >> 1; if (sec_base[mid] <= j) lo = mid; else hi = mid - 1; }
        unsigned int p = pairs[(size_t)lo * CHUNK + sec_lo[lo] + (j - sec_base[lo])];
        atomicAdd(&dhist[p >> 24], 1);
    }
    __syncthreads();

    if (t == 0) {
        int acc = 0;
        for (int i = 0; i < 256; ++i) { int v = dhist[i]; dhist[i] = acc; acc += v; }
    }
    __syncthreads();

    {
        int node = (b << 8) + t;
        if (node < N) off[node] = base_g + dhist[t];
        if (b == (int)gridDim.x - 1 && t == 0) off[N] = E;
    }
    dcur[t] = dhist[t];
    __syncthreads();

    for (int j = t; j < total; j += 256) {
        int lo = 0, hi = nchunk - 1;
        while (lo < hi) { int mid = (lo + hi + 1) >> 1; if (sec_base[mid] <= j) lo = mid; else hi = mid - 1; }
        unsigned int p = pairs[(size_t)lo * CHUNK + sec_lo[lo] + (j - sec_base[lo])];
        int slot = atomicAdd(&dcur[p >> 24], 1);
        unsigned int s = p & 0xFFFFFFu;
        if (slot < STAGE_CAP) stage[slot] = s;
        else csr[base_g + slot] = (int)s;
    }
    __syncthreads();

    int lim = min(total, STAGE_CAP);
    for (int j = t; j < lim; j += 256) csr[base_g + j] = (int)stage[j];
}

// ---------------------------------------------------------------------------
// Pull aggregation over bf16 hW rows, fused finish (round-5 version, 90us):
//   out[n] = (sum_{e in csr[n]} hW[src_e]) / outdeg[n] + b
// One wave per node; lane l owns col pair {2l, 2l+1} (one uint per row).
// ---------------------------------------------------------------------------
__global__ __launch_bounds__(256) void aggregate_bf16(const unsigned int* __restrict__ hw,
                                                      const int* __restrict__ off,
                                                      const int* __restrict__ csr,
                                                      const int* __restrict__ outdeg,
                                                      const float* __restrict__ bias,
                                                      float* __restrict__ out, int N) {
    const int wid  = (int)((blockIdx.x * blockDim.x + threadIdx.x) >> 6);
    const int lane = threadIdx.x & 63;
    const int nw   = (int)((gridDim.x * blockDim.x) >> 6);
    for (int n = wid; n < N; n += nw) {
        const int e0 = off[n], e1 = off[n + 1];
        float ax = 0.f, ay = 0.f;
        int e = e0;
        for (; e + 4 <= e1; e += 4) {
            int s0 = csr[e], s1 = csr[e + 1], s2 = csr[e + 2], s3 = csr[e + 3];
            unsigned int u0 = hw[(size_t)s0 * 64 + lane];
            unsigned int u1 = hw[(size_t)s1 * 64 + lane];
            unsigned int u2 = hw[(size_t)s2 * 64 + lane];
            unsigned int u3 = hw[(size_t)s3 * 64 + lane];
            ax += __uint_as_float(u0 << 16) + __uint_as_float(u1 << 16)
                + __uint_as_float(u2 << 16) + __uint_as_float(u3 << 16);
            ay += __uint_as_float(u0 & 0xffff0000u) + __uint_as_float(u1 & 0xffff0000u)
                + __uint_as_float(u2 & 0xffff0000u) + __uint_as_float(u3 & 0xffff0000u);
        }
        for (; e < e1; ++e) {
            unsigned int u = hw[(size_t)csr[e] * 64 + lane];
            ax += __uint_as_float(u << 16);
            ay += __uint_as_float(u & 0xffff0000u);
        }
        float sc = 1.0f / (float)outdeg[n];
        float2 bb = reinterpret_cast<const float2*>(bias)[lane];
        float2 o;
        o.x = ax * sc + bb.x;
        o.y = ay * sc + bb.y;
        reinterpret_cast<float2*>(out + (size_t)n * D)[lane] = o;
    }
}

// ---------------------------------------------------------------------------
// Tier-3 fallback: atomic scatter path (shape-independent)
// ---------------------------------------------------------------------------
__global__ void deg_kernel(const int* __restrict__ src, int* __restrict__ deg, int E) {
    int i = blockIdx.x * blockDim.x + threadIdx.x;
    int stride = gridDim.x * blockDim.x;
    for (; i < E; i += stride) atomicAdd(&deg[src[i]], 1);
}

__global__ void scatter_kernel(const float* __restrict__ h,
                               const int* __restrict__ src,
                               const int* __restrict__ dst,
                               float* __restrict__ agg, int E) {
    int wave   = (int)((blockIdx.x * blockDim.x + threadIdx.x) >> 6);
    int lane   = threadIdx.x & 63;
    int nwaves = (int)((gridDim.x * blockDim.x) >> 6);
    for (int e = wave; e < E; e += nwaves) {
        int s = src[e];
        int d = dst[e];
        const float2 v = reinterpret_cast<const float2*>(h + (size_t)s * D)[lane];
        float* arow = agg + (size_t)d * D + lane * 2;
        atomicAdd(arow + 0, v.x);
        atomicAdd(arow + 1, v.y);
    }
}

__global__ __launch_bounds__(256) void gemm_finish(float* __restrict__ out,
                                                   const float* __restrict__ Wm,
                                                   const float* __restrict__ bias,
                                                   const int* __restrict__ deg,
                                                   int N) {
    __shared__ __align__(16) float tile[64][D];
    const int r0 = blockIdx.x * 64;
    const int t  = threadIdx.x;

    #pragma unroll
    for (int i = 0; i < 8; ++i) {
        int flat4 = i * 256 + t;
        int r     = flat4 >> 5;
        int c4    = flat4 & 31;
        int gr    = r0 + r;
        float4 v  = make_float4(0.f, 0.f, 0.f, 0.f);
        if (gr < N) v = reinterpret_cast<const float4*>(out + (size_t)gr * D)[c4];
        reinterpret_cast<float4*>(&tile[r][c4 * 4])[0] = v;
    }
    __syncthreads();

    const int wsel = t >> 6;
    const int j0   = (t & 63) * 2;

    float acc[16][2];
    #pragma unroll
    for (int r = 0; r < 16; ++r) { acc[r][0] = 0.f; acc[r][1] = 0.f; }

    for (int k = 0; k < D; k += 4) {
        float2 w[4];
        #pragma unroll
        for (int kk = 0; kk < 4; ++kk)
            w[kk] = reinterpret_cast<const float2*>(Wm + (size_t)(k + kk) * D + j0)[0];
        #pragma unroll
        for (int r = 0; r < 16; ++r) {
            float4 a = reinterpret_cast<const float4*>(&tile[wsel * 16 + r][k])[0];
            acc[r][0] += a.x * w[0].x + a.y * w[1].x + a.z * w[2].x + a.w * w[3].x;
            acc[r][1] += a.x * w[0].y + a.y * w[1].y + a.z * w[2].y + a.w * w[3].y;
        }
    }

    const float2 bb = reinterpret_cast<const float2*>(bias + j0)[0];
    #pragma unroll
    for (int r = 0; r < 16; ++r) {
        int gr = r0 + wsel * 16 + r;
        if (gr < N) {
            float sc = 1.0f / (float)deg[gr];
            float2 o;
            o.x = acc[r][0] * sc + bb.x;
            o.y = acc[r][1] * sc + bb.y;
            reinterpret_cast<float2*>(out + (size_t)gr * D + j0)[0] = o;
        }
    }
}

// ---------------------------------------------------------------------------
extern "C" void kernel_launch(void* const* d_in, const int* in_sizes, int n_in,
                              void* d_out, int out_size, void* d_ws, size_t ws_size,
                              hipStream_t stream) {
    const float* h   = (const float*)d_in[0];
    const float* Wm  = (const float*)d_in[1];
    const float* bia = (const float*)d_in[2];
    const int*   src = (const int*)d_in[3];
    const int*   dst = (const int*)d_in[4];
    float*       out = (float*)d_out;

    const int N = in_sizes[0] / D;   // 100000
    const int E = in_sizes[3];       // 1700000

    const int nb      = (N + 255) >> 8;
    const int nchunk  = (E + CHUNK - 1) / CHUNK;
    const int gblocks = (N + 63) / 64;

    // ws (ints): outdeg[N] | tot[NB_MAX] | off[N+1] | cnt[nchunk*nb] |
    //            loff[nchunk*nb] | pairs[nchunk*CHUNK] | csr[E] | hw[N*64]
    size_t tier1_ints = (size_t)N + NB_MAX + (N + 1) + (size_t)2 * nchunk * nb
                      + (size_t)nchunk * CHUNK + (size_t)E + (size_t)N * 64;

    bool shape_ok = (N < (1 << 24)) && nb <= NB_MAX && nchunk <= NCHUNK_MAX;

    if (shape_ok && ws_size >= tier1_ints * sizeof(int)) {
        int* outdeg = (int*)d_ws;
        int* tot    = outdeg + N;
        int* off    = tot + NB_MAX;
        int* cnt_g  = off + (N + 1);
        int* loff_g = cnt_g + (size_t)nchunk * nb;
        unsigned int* pairs = (unsigned int*)(loff_g + (size_t)nchunk * nb);
        int* csr    = (int*)(pairs + (size_t)nchunk * CHUNK);
        unsigned int* hw = (unsigned int*)(csr + E);

        hipMemsetAsync(outdeg, 0, ((size_t)N + NB_MAX) * sizeof(int), stream);

        phase1<<<nchunk + gblocks, 256, 0, stream>>>(h, Wm, src, dst, pairs,
                                                     cnt_g, loff_g, outdeg, tot,
                                                     hw, E, nb, nchunk, N);

        csr_build<<<nb, 256, 0, stream>>>(pairs, cnt_g, loff_g, tot, off, csr,
                                          nb, nchunk, N, E);

        aggregate_bf16<<<(N + 3) / 4, 256, 0, stream>>>(hw, off, csr, outdeg, bia, out, N);
    } else {
        // fallback: atomic scatter path
        int* deg = (int*)d_ws;
        hipMemsetAsync(out, 0, (size_t)out_size * sizeof(float), stream);
        hipMemsetAsync(deg, 0, (size_t)N * sizeof(int), stream);
        deg_kernel<<<2048, 256, 0, stream>>>(src, deg, E);
        scatter_kernel<<<8192, 256, 0, stream>>>(h, src, dst, out, E);
        gemm_finish<<<(N + 63) / 64, 256, 0, stream>>>(out, Wm, bia, deg, N);
    }
}